// Round 1
// 26672.449 us; speedup vs baseline: 1.4987x; 1.4987x over previous
//
#include <hip/hip_runtime.h>
#include <math.h>

// Problem constants (fixed by setup_inputs)
#define V_   2
#define B_   8
#define S_   2048
#define D_   512
#define VOCAB_ 8192
#define STEPS_ 16
#define DECAY_ 0.999f
#define EPS_ 1e-6f
#define VB_  (V_ * B_)       // 16
#define R_   (VB_ * S_)      // 32768 token rows
#define RD_  ((long)R_ * D_) // 16777216 floats

typedef unsigned int u32;
typedef __attribute__((ext_vector_type(8)))  short bf16x8;   // MFMA A/B frag (4 VGPR)
typedef __attribute__((ext_vector_type(16))) float f32x16;   // MFMA C/D frag (16 VGPR)

enum Act { ACT_IDENT = 0, ACT_SIGMOID = 1, ACT_GELU = 2, ACT_PHI = 3 };

template <int ACT>
__device__ __forceinline__ float act_fn(float x) {
    if (ACT == ACT_SIGMOID) return 1.0f / (1.0f + __expf(-x));
    if (ACT == ACT_GELU)    return 0.5f * x * (1.0f + erff(x * 0.70710678118654752f));
    if (ACT == ACT_PHI)     return x > 0.0f ? x + 1.0f : __expf(x);  // elu(x)+1
    return x;
}

// ---------------------------------------------------------------------------
// Exact 3-way bf16 split (truncation): x == hi + mid + lo bit-exactly in fp32.
// hi = top 8 mantissa bits, r = x-hi exact (Sterbenz), mid = top 8 of r,
// r2 = r-mid exact and has <= 8 significant bits -> lo = r2 exactly.
// Returns the three bf16 bit patterns in the low 16 bits.
// ---------------------------------------------------------------------------
__device__ __forceinline__ void split3(float x, u32& h, u32& m, u32& l) {
    u32 bx = __float_as_uint(x);
    u32 hb = bx & 0xFFFF0000u;
    float r = x - __uint_as_float(hb);
    u32 rb = __float_as_uint(r);
    u32 mb = rb & 0xFFFF0000u;
    float r2 = r - __uint_as_float(mb);
    h = hb >> 16;
    m = mb >> 16;
    l = __float_as_uint(r2) >> 16;
}

// ---------------------------------------------------------------------------
// LDS layout (per operand): 3 bf16 planes, each [128 rows][32 k] ushort.
// Chunk swizzle: 16B chunk index c (k/8) stored at c ^ (row&3) ^ ((row>>2)&3)
// -> conflict-free ds_read_b128 frag reads and b64 staged writes.
// uint offsets: plane*2048 + row*16 + chunk*4 (+ half*2).
// ---------------------------------------------------------------------------

template <bool TRANS_A>
__device__ __forceinline__ void load_tile(const float* __restrict__ A,
                                          const float* __restrict__ Bm,
                                          int M, int N, int K,
                                          int rowBase, int colBase, int k0, int t,
                                          float4 (&av)[4], float4 (&bv)[4]) {
    if (!TRANS_A) {
        // A row-major [M][K]: float4 = 4 k at fixed row. id -> row=id>>3, kq=id&7
#pragma unroll
        for (int i = 0; i < 4; i++) {
            const int id = i * 256 + t;
            const int m = id >> 3, kq = id & 7;
            av[i] = *(const float4*)&A[(long)(rowBase + m) * K + k0 + kq * 4];
        }
    } else {
        // A is [K][M] (k-major): 4 coalesced stride-M dword loads = 4 k at fixed m
#pragma unroll
        for (int i = 0; i < 4; i++) {
            const int id = i * 256 + t;
            const int kq = id >> 7, m = id & 127;
            const float* p0 = &A[(long)(k0 + kq * 4) * M + rowBase + m];
            av[i].x = p0[0]; av[i].y = p0[M]; av[i].z = p0[2 * M]; av[i].w = p0[3 * M];
        }
    }
    // B is [K][N]: 4 coalesced stride-N dword loads = 4 k at fixed n
#pragma unroll
    for (int i = 0; i < 4; i++) {
        const int id = i * 256 + t;
        const int kq = id >> 7, n = id & 127;
        const float* p0 = &Bm[(long)(k0 + kq * 4) * N + colBase + n];
        bv[i].x = p0[0]; bv[i].y = p0[N]; bv[i].z = p0[2 * N]; bv[i].w = p0[3 * N];
    }
}

__device__ __forceinline__ void stage_quad(u32* base, int row, int kq, float4 v) {
    u32 h0, m0, l0, h1, m1, l1, h2, m2, l2, h3, m3, l3;
    split3(v.x, h0, m0, l0); split3(v.y, h1, m1, l1);
    split3(v.z, h2, m2, l2); split3(v.w, h3, m3, l3);
    const int sw = ((kq >> 1) ^ (row & 3) ^ ((row >> 2) & 3));
    u32* p = base + row * 16 + sw * 4 + (kq & 1) * 2;
    p[0]    = h0 | (h1 << 16); p[1]    = h2 | (h3 << 16);
    p[2048] = m0 | (m1 << 16); p[2049] = m2 | (m3 << 16);
    p[4096] = l0 | (l1 << 16); p[4097] = l2 | (l3 << 16);
}

// ---------------------------------------------------------------------------
// Split-bf16 MFMA GEMM: C = beta*C + Gate? ⊙ (alpha * act(A·B)), fp32 in/out.
// Numerically ≡ fp32 GEMM (drops only lo·lo ~ 2^-32 relative).
// 128×128 block tile, BK=32, 256 threads = 4 waves × (64×64 wave tile),
// v_mfma_f32_32x32x16_bf16, 8 plane-products per k-slice.
// Requires M%128==0, N%128==0, K%32==0 (holds for all call sites).
// ---------------------------------------------------------------------------
template <int ACT, bool HAS_GATE, bool TRANS_A>
__launch_bounds__(256)
__global__ void gemm_mfma(const float* __restrict__ A, const float* __restrict__ Bm,
                          float* __restrict__ C, const float* __restrict__ Gate,
                          int M, int N, int K,
                          long sA, long sB, long sC,
                          float alpha, float beta) {
    __shared__ u32 lds[12288];  // 48 KB: A planes [0,6144), B planes [6144,12288)
    const int bz = blockIdx.z;
    A  += (long)bz * sA;
    Bm += (long)bz * sB;
    C  += (long)bz * sC;
    const int colBase = blockIdx.x * 128;   // N-tile fastest -> neighbors share A panel (L2)
    const int rowBase = blockIdx.y * 128;
    const int t    = threadIdx.x;
    const int lane = t & 63;
    const int w    = t >> 6;          // wave 0..3 -> 2x2 wave grid
    const int wm   = (w >> 1) * 64;
    const int wn   = (w & 1) * 64;
    const int l31  = lane & 31;       // A-row / B-col within 32x32 frag
    const int lg   = lane >> 5;       // k-group

    f32x16 acc[2][2];
#pragma unroll
    for (int a = 0; a < 2; a++)
#pragma unroll
        for (int b = 0; b < 2; b++)
#pragma unroll
            for (int r = 0; r < 16; r++) acc[a][b][r] = 0.0f;

    float4 av[4], bv[4];
    load_tile<TRANS_A>(A, Bm, M, N, K, rowBase, colBase, 0, t, av, bv);

    for (int k0 = 0; k0 < K; k0 += 32) {
        __syncthreads();  // previous tile's frag reads complete
        // ---- split + stage current tile (waits on in-flight global loads)
#pragma unroll
        for (int i = 0; i < 4; i++) {
            const int id = i * 256 + t;
            int row, kq;
            if (!TRANS_A) { row = id >> 3; kq = id & 7; }
            else          { kq = id >> 7; row = id & 127; }
            stage_quad(lds, row, kq, av[i]);
        }
#pragma unroll
        for (int i = 0; i < 4; i++) {
            const int id = i * 256 + t;
            const int kq = id >> 7, n = id & 127;
            stage_quad(lds + 6144, n, kq, bv[i]);
        }
        __syncthreads();

        // ---- prefetch next tile's globals; latency hides under MFMA below
        if (k0 + 32 < K)
            load_tile<TRANS_A>(A, Bm, M, N, K, rowBase, colBase, k0 + 32, t, av, bv);

        // ---- fragment reads + 8-product MFMA
        bf16x8 af[2][2][3];  // [at][kh][plane]
#pragma unroll
        for (int at = 0; at < 2; at++) {
            const int m  = wm + at * 32 + l31;
            const int sx = (m & 3) ^ ((m >> 2) & 3);
#pragma unroll
            for (int kh = 0; kh < 2; kh++) {
                const int c = kh * 2 + lg;
#pragma unroll
                for (int p = 0; p < 3; p++)
                    af[at][kh][p] = *(const bf16x8*)&lds[p * 2048 + m * 16 + ((c ^ sx) << 2)];
            }
        }
#pragma unroll
        for (int bt = 0; bt < 2; bt++) {
            const int n  = wn + bt * 32 + l31;
            const int sx = (n & 3) ^ ((n >> 2) & 3);
            bf16x8 bf[2][3];
#pragma unroll
            for (int kh = 0; kh < 2; kh++) {
                const int c = kh * 2 + lg;
#pragma unroll
                for (int p = 0; p < 3; p++)
                    bf[kh][p] = *(const bf16x8*)&lds[6144 + p * 2048 + n * 16 + ((c ^ sx) << 2)];
            }
#define DO_PROD(pa, pb)                                                        \
    _Pragma("unroll")                                                          \
    for (int at = 0; at < 2; at++)                                             \
        _Pragma("unroll")                                                      \
        for (int kh = 0; kh < 2; kh++)                                         \
            acc[at][bt] = __builtin_amdgcn_mfma_f32_32x32x16_bf16(             \
                af[at][kh][pa], bf[kh][pb], acc[at][bt], 0, 0, 0);
            // hi*hi, hi*mid, mid*hi, mid*mid, hi*lo, lo*hi, mid*lo, lo*mid
            DO_PROD(0, 0) DO_PROD(0, 1) DO_PROD(1, 0) DO_PROD(1, 1)
            DO_PROD(0, 2) DO_PROD(2, 0) DO_PROD(1, 2) DO_PROD(2, 1)
#undef DO_PROD
        }
    }

    // ---- epilogue. C/D layout (m74/m101): col=lane&31, row=(r&3)+8*(r>>2)+4*(lane>>5)
#pragma unroll
    for (int at = 0; at < 2; at++)
#pragma unroll
        for (int bt = 0; bt < 2; bt++) {
            const long gc = colBase + wn + bt * 32 + l31;
#pragma unroll
            for (int r = 0; r < 16; r++) {
                const long gr = rowBase + wm + at * 32 + (r & 3) + 8 * (r >> 2) + 4 * lg;
                const long idx = gr * (long)N + gc;
                float vx = alpha * act_fn<ACT>(acc[at][bt][r]);
                if (HAS_GATE) vx *= Gate[idx];
                if (beta != 0.0f) vx += beta * C[idx];
                C[idx] = vx;
            }
        }
}

// ---------------------------------------------------------------------------
// RMS norm over last dim (D=512). One block (128 thr × float4) per row.
// ---------------------------------------------------------------------------
__launch_bounds__(128)
__global__ void rms_kernel(const float* __restrict__ X, float* __restrict__ Y) {
    const long row = blockIdx.x;
    const float4 v = *(const float4*)&X[row * D_ + threadIdx.x * 4];
    float ss = v.x * v.x + v.y * v.y + v.z * v.z + v.w * v.w;
#pragma unroll
    for (int off = 32; off > 0; off >>= 1) ss += __shfl_down(ss, off, 64);
    __shared__ float s2[2];
    if ((threadIdx.x & 63) == 0) s2[threadIdx.x >> 6] = ss;
    __syncthreads();
    const float tot = s2[0] + s2[1];
    const float sc = rsqrtf(tot * (1.0f / (float)D_) + EPS_);
    float4 o;
    o.x = v.x * sc; o.y = v.y * sc; o.z = v.z * sc; o.w = v.w * sc;
    *(float4*)&Y[row * D_ + threadIdx.x * 4] = o;
}

// ---------------------------------------------------------------------------
// Embedding gather: state[(v*B+b)*S+s, :] = emb[v, inputs[b,s], :]
// ---------------------------------------------------------------------------
__launch_bounds__(128)
__global__ void embed_kernel(const int* __restrict__ inputs, const float* __restrict__ emb,
                             float* __restrict__ state) {
    const int row = blockIdx.x;       // vb*S + s
    const int s  = row & (S_ - 1);
    const int vb = row >> 11;         // S_ = 2^11
    const int b  = vb & (B_ - 1);
    const int v  = vb >> 3;           // B_ = 2^3
    const int tok = inputs[b * S_ + s];
    const float4 val = *(const float4*)&emb[((long)v * VOCAB_ + tok) * D_ + threadIdx.x * 4];
    *(float4*)&state[(long)row * D_ + threadIdx.x * 4] = val;
}

// ---------------------------------------------------------------------------
// View-mean over V=2
// ---------------------------------------------------------------------------
__launch_bounds__(256)
__global__ void combine_kernel(const float* __restrict__ state, float* __restrict__ comb) {
    const long i = (long)blockIdx.x * 256 + threadIdx.x;  // float4 index
    const float4 a = ((const float4*)state)[i];
    const float4 c = ((const float4*)(state + (long)B_ * S_ * D_))[i];
    float4 o;
    o.x = 0.5f * (a.x + c.x); o.y = 0.5f * (a.y + c.y);
    o.z = 0.5f * (a.z + c.z); o.w = 0.5f * (a.w + c.w);
    ((float4*)comb)[i] = o;
}

extern "C" void kernel_launch(void* const* d_in, const int* in_sizes, int n_in,
                              void* d_out, int out_size, void* d_ws, size_t ws_size,
                              hipStream_t stream) {
    const int*   inputs = (const int*)d_in[0];
    const float* emb = (const float*)d_in[1];
    const float* Wg  = (const float*)d_in[2];
    const float* Wu  = (const float*)d_in[3];
    const float* Wd  = (const float*)d_in[4];
    const float* Wq  = (const float*)d_in[5];
    const float* Wk  = (const float*)d_in[6];
    const float* Wv  = (const float*)d_in[7];
    const float* Wv_o = (const float*)d_in[8];
    const float* Wlm = (const float*)d_in[9];
    float* out = (float*)d_out;

    float* ws    = (float*)d_ws;
    float* state = ws;               // R_*D_ (16M floats)
    float* nbuf  = ws + 1 * RD_;     // n / n2 / mixed
    float* gbuf  = ws + 2 * RD_;     // gate; reused for combined
    float* ubuf  = ws + 3 * RD_;     // R_*2D_ (32M floats)
    float* qbuf  = ws + 5 * RD_;
    float* kbuf  = ws + 6 * RD_;
    float* vbuf  = ws + 7 * RD_;
    float* accb  = ws + 8 * RD_;     // VB_*D_*D_ = 4M floats

    const float inv_s  = 1.0f / (float)S_;
    const float inv_sd = 0.044194173824159216f;  // 1/sqrt(512)

    hipMemsetAsync(accb, 0, (size_t)VB_ * D_ * D_ * sizeof(float), stream);
    embed_kernel<<<R_, 128, 0, stream>>>(inputs, emb, state);

    for (int step = 0; step < STEPS_; step++) {
        // n = rms(state)
        rms_kernel<<<R_, 128, 0, stream>>>(state, nbuf);
        // g = sigmoid(n @ Wg)                       [32768,512]x[512,512]
        gemm_mfma<ACT_SIGMOID, false, false><<<dim3(4, 256, 1), 256, 0, stream>>>(
            nbuf, Wg, gbuf, nullptr, R_, D_, D_, 0, 0, 0, 1.0f, 0.0f);
        // u = gelu(n @ Wu)                          [32768,512]x[512,1024]
        gemm_mfma<ACT_GELU, false, false><<<dim3(8, 256, 1), 256, 0, stream>>>(
            nbuf, Wu, ubuf, nullptr, R_, 2 * D_, D_, 0, 0, 0, 1.0f, 0.0f);
        // state += g ⊙ (u @ Wd)                     [32768,1024]x[1024,512]
        gemm_mfma<ACT_IDENT, true, false><<<dim3(4, 256, 1), 256, 0, stream>>>(
            ubuf, Wd, state, gbuf, R_, D_, 2 * D_, 0, 0, 0, 1.0f, 1.0f);
        // n2 = rms(state)
        rms_kernel<<<R_, 128, 0, stream>>>(state, nbuf);
        // q = phi(n2 @ Wq); k = phi(n2 @ Wk); v = n2 @ Wv
        gemm_mfma<ACT_PHI, false, false><<<dim3(4, 256, 1), 256, 0, stream>>>(
            nbuf, Wq, qbuf, nullptr, R_, D_, D_, 0, 0, 0, 1.0f, 0.0f);
        gemm_mfma<ACT_PHI, false, false><<<dim3(4, 256, 1), 256, 0, stream>>>(
            nbuf, Wk, kbuf, nullptr, R_, D_, D_, 0, 0, 0, 1.0f, 0.0f);
        gemm_mfma<ACT_IDENT, false, false><<<dim3(4, 256, 1), 256, 0, stream>>>(
            nbuf, Wv, vbuf, nullptr, R_, D_, D_, 0, 0, 0, 1.0f, 0.0f);
        // acc = DECAY*acc + (k^T v)*inv_s           batched 16: [512,2048]^T x [2048,512]
        gemm_mfma<ACT_IDENT, false, true><<<dim3(4, 4, VB_), 256, 0, stream>>>(
            kbuf, vbuf, accb, nullptr, D_, D_, S_,
            (long)S_ * D_, (long)S_ * D_, (long)D_ * D_, inv_s, DECAY_);
        // mixed = (q @ acc) * inv_sqrt_d            batched 16: [2048,512]x[512,512]
        gemm_mfma<ACT_IDENT, false, false><<<dim3(4, 16, VB_), 256, 0, stream>>>(
            qbuf, accb, nbuf, nullptr, S_, D_, D_,
            (long)S_ * D_, (long)D_ * D_, (long)S_ * D_, inv_sd, 0.0f);
        // state += mixed @ Wo
        gemm_mfma<ACT_IDENT, false, false><<<dim3(4, 256, 1), 256, 0, stream>>>(
            nbuf, Wv_o, state, nullptr, R_, D_, D_, 0, 0, 0, 1.0f, 1.0f);
    }

    // combined = mean over views; rms in-place; logits = comb @ Wlm
    combine_kernel<<<(B_ * S_ * D_ / 4) / 256, 256, 0, stream>>>(state, gbuf);
    rms_kernel<<<B_ * S_, 128, 0, stream>>>(gbuf, gbuf);
    gemm_mfma<ACT_IDENT, false, false><<<dim3(64, 128, 1), 256, 0, stream>>>(
        gbuf, Wlm, out, nullptr, B_ * S_, VOCAB_, D_, 0, 0, 0, 1.0f, 0.0f);
}